// Round 1
// baseline (3411.128 us; speedup 1.0000x reference)
//
#include <hip/hip_runtime.h>

// ConvLSTM fused kernel for MI355X (gfx950).
// Shapes: T=16, B=4, C=32, H=W=64, HID=64. 3x3 SAME convs, stride 1.
// One kernel launch per time step (sequential dependence through h,c).
// h state lives in d_out slices; c state lives in d_ws (4 MB).

#define HH   64
#define WW   64
#define HID  64
#define BATCH 4
#define CX   32
#define TSTEPS 16
#define TILE_W 32
#define TILE_H 8
#define CHUNK 16
#define LDS_STRIDE (TILE_W + 3)   // 35: conflict-free for stride-1 lane access

__device__ __forceinline__ float sigmoidf_(float x) {
    return 1.0f / (1.0f + __expf(-x));
}
__device__ __forceinline__ float tanhf_(float x) {
    // tanh(x) = 1 - 2/(exp(2x)+1); saturates correctly at +/-inf
    return 1.0f - 2.0f / (__expf(2.0f * x) + 1.0f);
}

__device__ __forceinline__ void load_tile(
    float tile[CHUNK][TILE_H + 2][LDS_STRIDE],
    const float* __restrict__ src,  // base of chunk: [CHUNK, H, W] contiguous
    int gy0, int gx0, int tid)
{
    const int NELEM = CHUNK * (TILE_H + 2) * (TILE_W + 2);  // 16*10*34 = 5440
    for (int idx = tid; idx < NELEM; idx += 256) {
        int c   = idx / ((TILE_H + 2) * (TILE_W + 2));
        int rem = idx - c * ((TILE_H + 2) * (TILE_W + 2));
        int r   = rem / (TILE_W + 2);
        int col = rem - r * (TILE_W + 2);
        int gy = gy0 - 1 + r;
        int gx = gx0 - 1 + col;
        float v = 0.0f;
        if (gy >= 0 && gy < HH && gx >= 0 && gx < WW)
            v = src[c * HH * WW + gy * WW + gx];
        tile[c][r][col] = v;
    }
}

__device__ __forceinline__ void accum_chunk(
    const float tile[CHUNK][TILE_H + 2][LDS_STRIDE],
    int ty, int tx,
    const float* __restrict__ w0p, const float* __restrict__ w1p,
    const float* __restrict__ w2p, const float* __restrict__ w3p,
    float& a0, float& a1, float& a2, float& a3)
{
    for (int ic = 0; ic < CHUNK; ++ic) {
        float w0[9], w1[9], w2[9], w3[9];
#pragma unroll
        for (int k = 0; k < 9; ++k) {
            w0[k] = w0p[ic * 9 + k];
            w1[k] = w1p[ic * 9 + k];
            w2[k] = w2p[ic * 9 + k];
            w3[k] = w3p[ic * 9 + k];
        }
#pragma unroll
        for (int dy = 0; dy < 3; ++dy) {
#pragma unroll
            for (int dx = 0; dx < 3; ++dx) {
                float v = tile[ic][ty + dy][tx + dx];
                int k = dy * 3 + dx;
                a0 = fmaf(v, w0[k], a0);
                a1 = fmaf(v, w1[k], a1);
                a2 = fmaf(v, w2[k], a2);
                a3 = fmaf(v, w3[k], a3);
            }
        }
    }
}

__global__ __launch_bounds__(256) void convlstm_step(
    const float* __restrict__ x_t,     // [B, CX, H, W]
    const float* __restrict__ h_prev,  // [B, HID, H, W] (null iff first)
    const float* __restrict__ w_x2h,   // [4*HID, CX, 3, 3]
    const float* __restrict__ b_x2h,   // [4*HID]
    const float* __restrict__ w_h2h,   // [4*HID, HID, 3, 3]
    const float* __restrict__ b_h2h,   // [4*HID]
    float* __restrict__ c_state,       // [B, HID, H, W] in d_ws
    float* __restrict__ h_out,         // [B, HID, H, W] = d_out slice t
    int first)
{
    __shared__ float tile[CHUNK][TILE_H + 2][LDS_STRIDE];  // ~22.4 KB

    const int tx  = threadIdx.x;            // 0..31
    const int ty  = threadIdx.y;            // 0..7
    const int tid = ty * 32 + tx;
    const int tileIdx = blockIdx.x;         // 0..15 (2 x-tiles * 8 y-tiles)
    const int hc = blockIdx.y;              // 0..HID-1
    const int b  = blockIdx.z;              // 0..BATCH-1
    const int gx0 = (tileIdx & 1) * TILE_W;
    const int gy0 = (tileIdx >> 1) * TILE_H;

    float a0 = 0.f, a1 = 0.f, a2 = 0.f, a3 = 0.f;

    // ---- x2h contribution: CX=32 input channels in chunks of 16 ----
    for (int c0 = 0; c0 < CX; c0 += CHUNK) {
        load_tile(tile, x_t + (size_t)(b * CX + c0) * HH * WW, gy0, gx0, tid);
        __syncthreads();
        accum_chunk(tile, ty, tx,
                    w_x2h + ((size_t)(0 * HID + hc) * CX + c0) * 9,
                    w_x2h + ((size_t)(1 * HID + hc) * CX + c0) * 9,
                    w_x2h + ((size_t)(2 * HID + hc) * CX + c0) * 9,
                    w_x2h + ((size_t)(3 * HID + hc) * CX + c0) * 9,
                    a0, a1, a2, a3);
        __syncthreads();
    }

    // ---- h2h contribution: HID=64 input channels in chunks of 16 ----
    if (!first) {
        for (int c0 = 0; c0 < HID; c0 += CHUNK) {
            load_tile(tile, h_prev + (size_t)(b * HID + c0) * HH * WW, gy0, gx0, tid);
            __syncthreads();
            accum_chunk(tile, ty, tx,
                        w_h2h + ((size_t)(0 * HID + hc) * HID + c0) * 9,
                        w_h2h + ((size_t)(1 * HID + hc) * HID + c0) * 9,
                        w_h2h + ((size_t)(2 * HID + hc) * HID + c0) * 9,
                        w_h2h + ((size_t)(3 * HID + hc) * HID + c0) * 9,
                        a0, a1, a2, a3);
            __syncthreads();
        }
    }

    // ---- LSTM cell update (gate order: i, f, g, o along out-channels) ----
    const float bi = b_x2h[0 * HID + hc] + b_h2h[0 * HID + hc];
    const float bf = b_x2h[1 * HID + hc] + b_h2h[1 * HID + hc];
    const float bg = b_x2h[2 * HID + hc] + b_h2h[2 * HID + hc];
    const float bo = b_x2h[3 * HID + hc] + b_h2h[3 * HID + hc];

    const float ig = sigmoidf_(a0 + bi);
    const float fg = sigmoidf_(a1 + bf);
    const float gg = tanhf_(a2 + bg);
    const float og = sigmoidf_(a3 + bo);

    const int ohw = ((b * HID + hc) * HH + (gy0 + ty)) * WW + (gx0 + tx);
    const float cprev = first ? 0.0f : c_state[ohw];
    const float cn = fg * cprev + ig * gg;
    c_state[ohw] = cn;
    h_out[ohw] = og * tanhf_(cn);
}

extern "C" void kernel_launch(void* const* d_in, const int* in_sizes, int n_in,
                              void* d_out, int out_size, void* d_ws, size_t ws_size,
                              hipStream_t stream) {
    const float* x     = (const float*)d_in[0];  // [T, B, CX, H, W]
    const float* w_x2h = (const float*)d_in[1];  // [4*HID, CX, 3, 3]
    const float* b_x2h = (const float*)d_in[2];  // [4*HID]
    const float* w_h2h = (const float*)d_in[3];  // [4*HID, HID, 3, 3]
    const float* b_h2h = (const float*)d_in[4];  // [4*HID]
    float* out = (float*)d_out;                  // [T, B, HID, H, W]
    float* c_state = (float*)d_ws;               // [B, HID, H, W] fp32 (4 MB)

    const size_t x_step = (size_t)BATCH * CX * HH * WW;
    const size_t h_step = (size_t)BATCH * HID * HH * WW;

    dim3 grid(16, HID, BATCH);   // (2 x-tiles * 8 y-tiles, hid, batch) = 4096 blocks
    dim3 block(TILE_W, TILE_H);  // 256 threads

    for (int t = 0; t < TSTEPS; ++t) {
        const float* x_t    = x + (size_t)t * x_step;
        const float* h_prev = (t == 0) ? nullptr : out + (size_t)(t - 1) * h_step;
        float* h_out        = out + (size_t)t * h_step;
        convlstm_step<<<grid, block, 0, stream>>>(
            x_t, h_prev, w_x2h, b_x2h, w_h2h, b_h2h, c_state, h_out, t == 0 ? 1 : 0);
    }
}